// Round 2
// baseline (16198.665 us; speedup 1.0000x reference)
//
#include <hip/hip_runtime.h>

// ---------------- constants ----------------
static constexpr int BB = 32, TI = 2000, TT = 1000, CIN = 80, F = 256, KW = 11;
static constexpr int G4 = 2048, V = 29;
static constexpr int MROWS = TT * BB;   // 32000
static constexpr int KC = 896;          // conv K (11*80=880) padded to mult of 64
static constexpr int CH = 100;          // steps per recurrence chunk
static constexpr int NCH = TT / CH;     // 10 chunks
static constexpr int CROWS = CH * BB;   // 3200 rows per chunk

using short8 = __attribute__((ext_vector_type(8))) short;
using f32x4  = __attribute__((ext_vector_type(4))) float;

#define DEV __device__ __forceinline__

DEV ushort f2bf(float f) {
  unsigned u = __float_as_uint(f);
  unsigned r = (u + 0x7FFFu + ((u >> 16) & 1u)) >> 16;
  return (ushort)r;
}
DEV float bf2f(ushort h) { return __uint_as_float(((unsigned)h) << 16); }
DEV float sigm(float x) { return 1.f / (1.f + __expf(-x)); }
DEV float tanhft(float x) { return 1.f - 2.f / (__expf(2.f * x) + 1.f); }

// ---------------- prep kernels ----------------
__global__ void k_zero(int* p, int n) {
  int i = blockIdx.x * blockDim.x + threadIdx.x;
  if (i < n) p[i] = 0;
}

// conv_w [11][80][256] -> CW [256][896] bf16 (K padded w/ zeros)
__global__ void k_convw(const float* __restrict__ w, ushort* __restrict__ dst) {
  int idx = blockIdx.x * blockDim.x + threadIdx.x;
  if (idx >= F * KC) return;
  int f = idx / KC, kk = idx % KC;
  float v = (kk < KW * CIN) ? w[(size_t)kk * F + f] : 0.f;
  dst[idx] = f2bf(v);
}

// src [K][N] fp32 -> dst [N][K] bf16
__global__ void k_transp(const float* __restrict__ src, ushort* __restrict__ dst, int K, int N) {
  int idx = blockIdx.x * blockDim.x + threadIdx.x;
  if (idx >= K * N) return;
  int n = idx / K, k = idx % K;
  dst[idx] = f2bf(src[(size_t)k * N + n]);
}

// wh [512][2048] fp32 (f and b) -> packed MFMA B-fragments for the rec kernel.
// linear idx = ((((d*16+part)*8+w)*16+kk)*64+lane)*8 + j
__global__ void k_whr(const float* __restrict__ whf, const float* __restrict__ whb,
                      ushort* __restrict__ dst) {
  int idx = blockIdx.x * blockDim.x + threadIdx.x;
  if (idx >= (1 << 21)) return;
  int j = idx & 7, lane = (idx >> 3) & 63, kk = (idx >> 9) & 15;
  int w = (idx >> 13) & 7, part = (idx >> 16) & 15, d = (idx >> 20) & 1;
  int c16 = lane & 15, q = lane >> 4;
  int jj = w * 4 + (c16 >> 2), g = c16 & 3;
  int k = kk * 32 + q * 8 + j;
  int col = g * 512 + part * 32 + jj;
  const float* s = d ? whb : whf;
  dst[idx] = f2bf(s[(size_t)k * G4 + col]);
}

// x [32][2000][80] fp32 -> A0 [3200][896] bf16 im2col chunk (rows: (pos-pos0)*32+b)
__global__ void k_im2col(const float* __restrict__ x, ushort* __restrict__ A0, int pos0) {
  int idx = blockIdx.x * blockDim.x + threadIdx.x;
  if (idx >= CROWS * KC) return;
  int row = idx / KC, kk = idx % KC;
  int pos = pos0 + (row >> 5), b = row & 31;
  float v = 0.f;
  if (kk < KW * CIN) {
    int k = kk / CIN, c = kk % CIN;
    int tx = 2 * pos + k - 4;
    if (tx >= 0 && tx < TI) v = x[((size_t)b * TI + tx) * CIN + c];
  }
  A0[idx] = f2bf(v);
}

// ---------------- GEMM: C[.,N] = A[.,K] * BT[N,K]^T + bias (bf16 in/out, fp32 acc) ----------
// grid (Mtiles, N/128). 128x128 tile, BK=64, 4 waves, 4x4 16x16 frags/wave. A,C pre-offset.
__global__ __launch_bounds__(256, 2) void k_gemm(const ushort* __restrict__ A,
                                                 const ushort* __restrict__ BT,
                                                 const float* __restrict__ bias,
                                                 ushort* __restrict__ C,
                                                 int N, int K, int relu) {
  __shared__ ushort As[128 * 64];
  __shared__ ushort Bs[128 * 64];
  const int tid = threadIdx.x;
  const int lane = tid & 63, wid = tid >> 6;
  const int wm = wid >> 1, wn = wid & 1;
  const int l16 = lane & 15, q = lane >> 4;
  const int bm = blockIdx.x, bn = blockIdx.y;
  const int srow = tid >> 1, scol = (tid & 1) * 32;
  const ushort* ga = A + (size_t)(bm * 128 + srow) * K + scol;
  const ushort* gb = BT + (size_t)(bn * 128 + srow) * K + scol;

  f32x4 acc[4][4] = {};
  uint4 va[4], vb[4];
#pragma unroll
  for (int i = 0; i < 4; i++) { va[i] = ((const uint4*)ga)[i]; vb[i] = ((const uint4*)gb)[i]; }

  for (int k0 = 0; k0 < K; k0 += 64) {
    __syncthreads();
#pragma unroll
    for (int i = 0; i < 4; i++) {
      *(uint4*)&As[srow * 64 + scol + i * 8] = va[i];
      *(uint4*)&Bs[srow * 64 + scol + i * 8] = vb[i];
    }
    __syncthreads();
    if (k0 + 64 < K) {
      const ushort* na = ga + k0 + 64;
      const ushort* nb = gb + k0 + 64;
#pragma unroll
      for (int i = 0; i < 4; i++) { va[i] = ((const uint4*)na)[i]; vb[i] = ((const uint4*)nb)[i]; }
    }
#pragma unroll
    for (int kk = 0; kk < 2; kk++) {
      short8 af[4], bf[4];
#pragma unroll
      for (int mt = 0; mt < 4; mt++)
        af[mt] = *(const short8*)&As[(wm * 64 + mt * 16 + l16) * 64 + kk * 32 + q * 8];
#pragma unroll
      for (int nt = 0; nt < 4; nt++)
        bf[nt] = *(const short8*)&Bs[(wn * 64 + nt * 16 + l16) * 64 + kk * 32 + q * 8];
#pragma unroll
      for (int mt = 0; mt < 4; mt++)
#pragma unroll
        for (int nt = 0; nt < 4; nt++)
          acc[mt][nt] = __builtin_amdgcn_mfma_f32_16x16x32_bf16(af[mt], bf[nt], acc[mt][nt], 0, 0, 0);
    }
  }
#pragma unroll
  for (int mt = 0; mt < 4; mt++) {
#pragma unroll
    for (int nt = 0; nt < 4; nt++) {
      int col = bn * 128 + wn * 64 + nt * 16 + l16;
      float bv = bias[col];
#pragma unroll
      for (int r = 0; r < 4; r++) {
        int row = bm * 128 + wm * 64 + mt * 16 + q * 4 + r;
        float v = acc[mt][nt][r] + bv;
        if (relu) v = fmaxf(v, 0.f);
        C[(size_t)row * N + col] = f2bf(v);
      }
    }
  }
}

// ---------------- persistent BiLSTM recurrence chunk (one layer, both directions) ----------
// 32 blocks x 512 threads; processes global steps [s0, s0+CH).
// block = (d<<4)|part: d=dir, part owns h-cols [part*32, part*32+32).
__global__ __launch_bounds__(512, 1) void k_rec(const ushort* __restrict__ xgf,
                                                const ushort* __restrict__ xgb,
                                                const ushort* __restrict__ whr,
                                                ushort* __restrict__ hout,
                                                int* __restrict__ flags,
                                                float* __restrict__ cstbuf,
                                                int s0) {
  __shared__ ushort hs[32 * 512];  // 32KB, rows XOR-swizzled by ((row&7)<<4) bytes
  const int tid = threadIdx.x, lane = tid & 63, w = tid >> 6;
  const int part = blockIdx.x & 15, d = blockIdx.x >> 4;
  const int l16 = lane & 15, q = lane >> 4;
  const ushort* xg = d ? xgb : xgf;
  int* flg = flags + d * 1000;
  float* cs = cstbuf + ((size_t)blockIdx.x * 512 + tid) * 8;

  short8 wf[16];
  {
    const ushort* p = whr + (((size_t)(d * 16 + part) * 8 + w) * 16 * 64 + lane) * 8;
#pragma unroll
    for (int kk = 0; kk < 16; kk++) wf[kk] = *(const short8*)(p + (size_t)kk * 64 * 8);
  }
  const int jj = w * 4 + (l16 >> 2), g = l16 & 3;
  const int gcol = g * 512 + part * 32 + jj;   // column in xg [.,2048], gate order i,f,g,o
  const int hcol = part * 32 + jj;             // column in h [.,512]
  float cst[2][4];
#pragma unroll
  for (int mt = 0; mt < 2; mt++)
#pragma unroll
    for (int r = 0; r < 4; r++) cst[mt][r] = (s0 == 0) ? 0.f : cs[mt * 4 + r];

  for (int ls = 0; ls < CH; ls++) {
    const int s = s0 + ls;
    const int pos = d ? (999 - s) : s;
    const int lp = d ? (CH - 1 - ls) : ls;    // local row block in xg chunk buffer
    // prefetch xt (independent of h -> overlaps poll latency)
    ushort xtv[2][4];
#pragma unroll
    for (int mt = 0; mt < 2; mt++)
#pragma unroll
      for (int r = 0; r < 4; r++) {
        int bt = mt * 16 + q * 4 + r;
        xtv[mt][r] = xg[((size_t)lp * 32 + bt) * G4 + gcol];
      }

    if (s == 0) {
      uint4 z4 = {0, 0, 0, 0};
#pragma unroll
      for (int i = 0; i < 4; i++) ((uint4*)hs)[tid * 4 + i] = z4;
    } else {
      if (ls > 0) {  // first step of a chunk: prev step finished in prior dispatch
        if (tid == 0) {
          while (__hip_atomic_load(flg + (s - 1), __ATOMIC_RELAXED, __HIP_MEMORY_SCOPE_AGENT) < 16) {}
          (void)__hip_atomic_load(flg + (s - 1), __ATOMIC_ACQUIRE, __HIP_MEMORY_SCOPE_AGENT);
        }
        __syncthreads();
      }
      const int ppos = d ? pos + 1 : pos - 1;
      const int b = tid >> 4, cb = (tid & 15) * 64;
      const ushort* g0 = hout + ((size_t)ppos * 32 + b) * 1024 + d * 512 + (cb >> 1);
      uint4 v0 = *(const uint4*)(g0);
      uint4 v1 = *(const uint4*)(g0 + 8);
      uint4 v2 = *(const uint4*)(g0 + 16);
      uint4 v3 = *(const uint4*)(g0 + 24);
      const int swz = (b & 7) << 4;
      char* L = (char*)hs + b * 1024;
      *(uint4*)(L + ((cb + 0) ^ swz))  = v0;
      *(uint4*)(L + ((cb + 16) ^ swz)) = v1;
      *(uint4*)(L + ((cb + 32) ^ swz)) = v2;
      *(uint4*)(L + ((cb + 48) ^ swz)) = v3;
    }
    __syncthreads();

    f32x4 za[2] = {};
#pragma unroll
    for (int kk = 0; kk < 16; kk++) {
#pragma unroll
      for (int mt = 0; mt < 2; mt++) {
        int row = mt * 16 + l16;
        int cb = kk * 64 + q * 16;
        short8 a = *(const short8*)((char*)hs + row * 1024 + (cb ^ ((row & 7) << 4)));
        za[mt] = __builtin_amdgcn_mfma_f32_16x16x32_bf16(a, wf[kk], za[mt], 0, 0, 0);
      }
    }

#pragma unroll
    for (int mt = 0; mt < 2; mt++) {
#pragma unroll
      for (int r = 0; r < 4; r++) {
        int bt = mt * 16 + q * 4 + r;
        float z = za[mt][r] + bf2f(xtv[mt][r]);
        int base = lane & ~3;
        float zi = __shfl(z, base + 0);
        float zf = __shfl(z, base + 1);
        float zg = __shfl(z, base + 2);
        float zo = __shfl(z, base + 3);
        float cn = sigm(zf) * cst[mt][r] + sigm(zi) * tanhft(zg);
        cst[mt][r] = cn;
        float hv = sigm(zo) * tanhft(cn);
        if (g == 0) hout[((size_t)pos * 32 + bt) * 1024 + d * 512 + hcol] = f2bf(hv);
      }
    }
    __syncthreads();  // drains vmcnt: all h stores retired before release
    if (tid == 0) __hip_atomic_fetch_add(flg + s, 1, __ATOMIC_RELEASE, __HIP_MEMORY_SCOPE_AGENT);
  }
#pragma unroll
  for (int mt = 0; mt < 2; mt++)
#pragma unroll
    for (int r = 0; r < 4; r++) cs[mt * 4 + r] = cst[mt][r];
}

// ---------------- dense: out[b][pos][29] = h2[row,1024] . W[1024,29] + bias ------------
__global__ __launch_bounds__(256, 2) void k_dense(const ushort* __restrict__ h2,
                                                  const float* __restrict__ wd,
                                                  const float* __restrict__ bd,
                                                  float* __restrict__ out) {
  __shared__ ushort rs[8 * 1024];
  const int tid = threadIdx.x;
  const int r0 = blockIdx.x * 8;
  const uint4* src = (const uint4*)(h2 + (size_t)r0 * 1024);
#pragma unroll
  for (int i = 0; i < 4; i++) ((uint4*)rs)[tid * 4 + i] = src[tid * 4 + i];
  __syncthreads();
  if (tid < 8 * V) {
    const int rr = tid / V, v = tid % V;
    float acc = bd[v];
    const ushort* rp = rs + rr * 1024;
#pragma unroll 8
    for (int k = 0; k < 1024; k++) acc += bf2f(rp[k]) * wd[(size_t)k * V + v];
    const int row = r0 + rr, pos = row >> 5, b = row & 31;
    out[((size_t)b * TT + pos) * V + v] = acc;
  }
}

// ---------------- host ----------------
extern "C" void kernel_launch(void* const* d_in, const int* in_sizes, int n_in,
                              void* d_out, int out_size, void* d_ws, size_t ws_size,
                              hipStream_t stream) {
  const float* x      = (const float*)d_in[0];
  const float* conv_w = (const float*)d_in[1];
  const float* conv_b = (const float*)d_in[2];
  const float* wi1f = (const float*)d_in[3];
  const float* wh1f = (const float*)d_in[4];
  const float* b1f  = (const float*)d_in[5];
  const float* wi1b = (const float*)d_in[6];
  const float* wh1b = (const float*)d_in[7];
  const float* b1b  = (const float*)d_in[8];
  const float* wi2f = (const float*)d_in[9];
  const float* wh2f = (const float*)d_in[10];
  const float* b2f  = (const float*)d_in[11];
  const float* wi2b = (const float*)d_in[12];
  const float* wh2b = (const float*)d_in[13];
  const float* b2b  = (const float*)d_in[14];
  const float* wd   = (const float*)d_in[15];
  const float* bd   = (const float*)d_in[16];
  float* out = (float*)d_out;

  char* ws = (char*)d_ws;
  size_t o = 0;
  auto alloc = [&](size_t sz) { size_t r = o; o = (o + sz + 255) & ~(size_t)255; return r; };
  const size_t oH2  = alloc((size_t)MROWS * 1024 * 2);  // 65.5MB; Y overlays first 16.4MB
  const size_t oY   = oH2;                              // conv out, dead before rec2 writes H2
  const size_t oXGF = alloc((size_t)CROWS * G4 * 2);    // 13.1MB chunk buffer (also im2col scratch)
  const size_t oXGB = alloc((size_t)CROWS * G4 * 2);
  const size_t oH1  = alloc((size_t)MROWS * 1024 * 2);
  const size_t oCW  = alloc((size_t)F * KC * 2);
  const size_t oW1F = alloc((size_t)G4 * F * 2);
  const size_t oW1B = alloc((size_t)G4 * F * 2);
  const size_t oW2F = alloc((size_t)G4 * 1024 * 2);
  const size_t oW2B = alloc((size_t)G4 * 1024 * 2);
  const size_t oR1  = alloc((size_t)(1 << 21) * 2);
  const size_t oR2  = alloc((size_t)(1 << 21) * 2);
  const size_t oCST = alloc((size_t)32 * 512 * 8 * 4);
  const size_t oFL  = alloc(4000 * 4);
  if (ws_size < o) return;  // workspace insufficient (~177MB needed)

  ushort* H2  = (ushort*)(ws + oH2);
  ushort* Y   = (ushort*)(ws + oY);
  ushort* XGF = (ushort*)(ws + oXGF);
  ushort* XGB = (ushort*)(ws + oXGB);
  ushort* H1  = (ushort*)(ws + oH1);
  ushort* CW  = (ushort*)(ws + oCW);
  ushort* W1F = (ushort*)(ws + oW1F);
  ushort* W1B = (ushort*)(ws + oW1B);
  ushort* W2F = (ushort*)(ws + oW2F);
  ushort* W2B = (ushort*)(ws + oW2B);
  ushort* R1  = (ushort*)(ws + oR1);
  ushort* R2  = (ushort*)(ws + oR2);
  float*  CST = (float*)(ws + oCST);
  int*    FL  = (int*)(ws + oFL);

  hipLaunchKernelGGL(k_zero, dim3(16), dim3(256), 0, stream, FL, 4000);
  hipLaunchKernelGGL(k_convw, dim3((F * KC + 255) / 256), dim3(256), 0, stream, conv_w, CW);
  hipLaunchKernelGGL(k_transp, dim3((F * G4 + 255) / 256), dim3(256), 0, stream, wi1f, W1F, F, G4);
  hipLaunchKernelGGL(k_transp, dim3((F * G4 + 255) / 256), dim3(256), 0, stream, wi1b, W1B, F, G4);
  hipLaunchKernelGGL(k_transp, dim3((1024 * G4 + 255) / 256), dim3(256), 0, stream, wi2f, W2F, 1024, G4);
  hipLaunchKernelGGL(k_transp, dim3((1024 * G4 + 255) / 256), dim3(256), 0, stream, wi2b, W2B, 1024, G4);
  hipLaunchKernelGGL(k_whr, dim3((1 << 21) / 256), dim3(256), 0, stream, wh1f, wh1b, R1);
  hipLaunchKernelGGL(k_whr, dim3((1 << 21) / 256), dim3(256), 0, stream, wh2f, wh2b, R2);

  // conv as chunked im2col + GEMM (+bias+relu) -> Y bf16 [32000,256]
  for (int p = 0; p < NCH; ++p) {
    hipLaunchKernelGGL(k_im2col, dim3((CROWS * KC + 255) / 256), dim3(256), 0, stream,
                       x, XGF, p * CH);
    hipLaunchKernelGGL(k_gemm, dim3(CROWS / 128, F / 128), dim3(256), 0, stream,
                       XGF, CW, conv_b, Y + (size_t)p * CROWS * F, F, KC, 1);
  }
  // layer 1: chunked projections + recurrence -> H1 [1000][32][1024]
  for (int p = 0; p < NCH; ++p) {
    hipLaunchKernelGGL(k_gemm, dim3(CROWS / 128, G4 / 128), dim3(256), 0, stream,
                       Y + (size_t)p * CROWS * F, W1F, b1f, XGF, G4, F, 0);
    hipLaunchKernelGGL(k_gemm, dim3(CROWS / 128, G4 / 128), dim3(256), 0, stream,
                       Y + (size_t)(NCH - 1 - p) * CROWS * F, W1B, b1b, XGB, G4, F, 0);
    hipLaunchKernelGGL(k_rec, dim3(32), dim3(512), 0, stream, XGF, XGB, R1, H1, FL, CST, p * CH);
  }
  // layer 2: chunked projections + recurrence -> H2
  for (int p = 0; p < NCH; ++p) {
    hipLaunchKernelGGL(k_gemm, dim3(CROWS / 128, G4 / 128), dim3(256), 0, stream,
                       H1 + (size_t)p * CROWS * 1024, W2F, b2f, XGF, G4, 1024, 0);
    hipLaunchKernelGGL(k_gemm, dim3(CROWS / 128, G4 / 128), dim3(256), 0, stream,
                       H1 + (size_t)(NCH - 1 - p) * CROWS * 1024, W2B, b2b, XGB, G4, 1024, 0);
    hipLaunchKernelGGL(k_rec, dim3(32), dim3(512), 0, stream, XGF, XGB, R2, H2, FL + 2000, CST, p * CH);
  }
  // dense
  hipLaunchKernelGGL(k_dense, dim3(MROWS / 8), dim3(256), 0, stream, H2, wd, bd, out);
}